// Round 9
// baseline (598.399 us; speedup 1.0000x reference)
//
#include <hip/hip_runtime.h>
#include <stdint.h>

#define NN 50000
#define NPAD 50048   // padded row count; rows NN..NPAD-1 of g are ZEROED (mask rows)
#define NE 800000
#define DIM 256
#define NCHUNK 8     // 8 feature chunks of 32 (64 B bf16) -> one chunk per XCD L2
#define ZROW NN      // zeroed pad row used to mask out-of-degree gathers
#define GLC 64       // u16 slots per dest (128 B row); slots: edges, self at deg, rest ZROW

typedef __attribute__((ext_vector_type(8))) short short8;
typedef __attribute__((ext_vector_type(8))) unsigned short ushort8v;
typedef __attribute__((ext_vector_type(4))) float floatx4;
typedef __attribute__((ext_vector_type(2))) float float2v;
typedef __attribute__((ext_vector_type(4))) uint32_t uint4v;
typedef __attribute__((ext_vector_type(4))) int int4v;

__device__ __forceinline__ uint16_t f2bf(float f) {
  union { float f; uint32_t u; } v; v.f = f;
  uint32_t r = v.u + 0x7fffu + ((v.u >> 16) & 1u);
  return (uint16_t)(r >> 16);
}
__device__ __forceinline__ float bf2f(uint16_t h) {
  union { uint32_t u; float f; } v; v.u = ((uint32_t)h) << 16;
  return v.f;
}

// acc pair += (bf16 lo, bf16 hi) of dword u, via packed fp32 add
__device__ __forceinline__ void pkacc(float2v& a, uint32_t u) {
  union { uint32_t u; float f; } lo, hi;
  lo.u = u << 16;
  hi.u = u & 0xffff0000u;
  float2v val;
  val[0] = lo.f;
  val[1] = hi.f;
  asm("v_pk_add_f32 %0, %1, %0" : "+v"(a) : "v"(val));
}

// async global->LDS, 16B per lane; dest = wave-uniform base + lane*16
__device__ __forceinline__ void stage16(const uint16_t* gp, short* lbase, int lane) {
#if __has_builtin(__builtin_amdgcn_global_load_lds)
  __builtin_amdgcn_global_load_lds((__attribute__((address_space(1))) void*)gp,
                                   (__attribute__((address_space(3))) void*)lbase,
                                   16, 0, 0);
#else
  *(ushort8v*)((uint16_t*)lbase + lane * 8) = *(const ushort8v*)gp;
#endif
}

// ---------------- merged init ----------------
// blocks 0..1562: prefill gl(u16) with ZROW (8 u16/thread), zero fill, zero bins,
//                 zero g pad rows; blocks 1563..1690: transpose W1/W2 -> Wt (bf16).
__global__ __launch_bounds__(256) void k_init(int* __restrict__ fill, uint16_t* __restrict__ g,
                                              uint16_t* __restrict__ gl,
                                              int* __restrict__ bins,
                                              const float* __restrict__ W1,
                                              const float* __restrict__ W2,
                                              uint16_t* __restrict__ Wt1,
                                              uint16_t* __restrict__ Wt2) {
  __shared__ float t[32][33];
  if (blockIdx.x >= 1563) {  // prep_w part
    int bid = blockIdx.x - 1563;           // 0..127
    const float* W = (bid < 64) ? W1 : W2;
    uint16_t* Wt = (bid < 64) ? Wt1 : Wt2;
    bid &= 63;
    int bx = bid & 7, by = bid >> 3;
    int tx = threadIdx.x & 31, ty = threadIdx.x >> 5;  // 32 x 8
#pragma unroll
    for (int q = 0; q < 4; ++q)
      t[ty + q * 8][tx] = W[(size_t)(by * 32 + ty + q * 8) * 256 + bx * 32 + tx];
    __syncthreads();
#pragma unroll
    for (int q = 0; q < 4; ++q)
      Wt[(size_t)(bx * 32 + ty + q * 8) * 256 + by * 32 + tx] = f2bf(t[tx][ty + q * 8]);
    return;
  }
  int i = blockIdx.x * 256 + threadIdx.x;
  if (i < 400000) {                              // NN*GLC/8 = 400000 ushort8 stores
    ushort8v z8 = {ZROW, ZROW, ZROW, ZROW, ZROW, ZROW, ZROW, ZROW};
    ((ushort8v*)gl)[i] = z8;
  }
  if (i < NPAD / 4) {
    int4v zz = {0, 0, 0, 0};
    ((int4v*)fill)[i] = zz;                      // NPAD/4 = 12512
  }
  if (i < 32) {
    int4v zz = {0, 0, 0, 0};
    ((int4v*)bins)[i] = zz;                      // bins[64] + cursors[64]
  }
  if (blockIdx.x < NCHUNK) {
    uint32_t* q = (uint32_t*)(g + ((size_t)blockIdx.x * NPAD + NN) * 32);  // 48*32 u16
    for (int k = threadIdx.x; k < 768; k += 256) q[k] = 0;
  }
}

// fill gather list directly from the edge list; fill[] doubles as degree array
__global__ __launch_bounds__(256) void k_fill(const int* __restrict__ src,
                                              const int* __restrict__ dst,
                                              int* __restrict__ fill,
                                              uint16_t* __restrict__ gl) {
  int e = blockIdx.x * 256 + threadIdx.x;
  if (e < NE) {
    int d = dst[e];
    int old = atomicAdd(&fill[d], 1);
    if (old < GLC - 1) gl[d * GLC + old] = (uint16_t)src[e];  // last slot kept for self
  }
}

// place self at slot deg; histogram degrees into 64 bins (for counting sort)
__global__ __launch_bounds__(256) void k_degbins(const int* __restrict__ fill,
                                                 uint16_t* __restrict__ gl,
                                                 int* __restrict__ bins) {
  int i = blockIdx.x * 256 + threadIdx.x;
  if (i < NN) {
    int deg = fill[i];
    if (deg < GLC) gl[i * GLC + deg] = (uint16_t)i;
    atomicAdd(&bins[deg < 63 ? deg : 63], 1);
  }
}

// counting-sort scatter: perm = dest ids sorted by degree (in-bin order arbitrary)
__global__ __launch_bounds__(256) void k_scatter(const int* __restrict__ fill,
                                                 int* __restrict__ bins,
                                                 uint16_t* __restrict__ perm) {
  __shared__ int soff[64];
  if (threadIdx.x == 0) {
    int a = 0;
    for (int k = 0; k < 64; ++k) { soff[k] = a; a += bins[k]; }
  }
  __syncthreads();
  int i = blockIdx.x * 256 + threadIdx.x;
  if (i < NN) {
    int deg = fill[i];
    if (deg > 63) deg = 63;
    int pos = soff[deg] + atomicAdd(&bins[64 + deg], 1);  // bins[64..127] = cursors
    perm[pos] = (uint16_t)i;
  }
}

// ------------- GEMM: BM=128, BN=128, 2-phase double-buffered pipeline -------------
// SPLIT=1: A = x fp32 node-major, hi/lo bf16 split in-register (fused split).
// SPLIT=0: A = bf16 chunk-major [8][NPAD][32] via global_load_lds.
// grid (NPAD/128, 2); one barrier per K-step; C chunk-major, pre-scaled by
// dinv(row) = rsqrt(deg+1) computed from fill[] in the epilogue.
#define BM 128
#define BK 32

template <int SPLIT>
__global__ __launch_bounds__(256) void k_gemm(const uint16_t* __restrict__ Ab,
                                              const float* __restrict__ Af,
                                              const uint16_t* __restrict__ Wt,
                                              const int* __restrict__ degp,
                                              uint16_t* __restrict__ C, int M) {
  __shared__ short Ash[2][BM * BK];   // 16 KB
  __shared__ short Asl[2][BM * BK];   // 16 KB (used only if SPLIT)
  __shared__ short Bs[2][128 * BK];   // 16 KB

  const int tid = threadIdx.x;
  const int wave = tid >> 6, lane = tid & 63;
  const int wm = wave >> 1, wn = wave & 1;
  const int m16 = lane & 15, q = lane >> 4;
  const int rowBase = blockIdx.x * BM;
  const int colBase = blockIdx.y * 128;
  const int rsub = lane >> 2;       // 0..15
  const int kch = (lane & 3) * 8;   // elem offset within 32-chunk

  auto stageB = [&](int kc, int buf) {
#pragma unroll
    for (int p2 = 0; p2 < 2; ++p2) {
      int n = p2 * 64 + wave * 16 + rsub;
      stage16(Wt + (size_t)(colBase + n) * 256 + kc * 32 + kch,
              &Bs[buf][(p2 * 64 + wave * 16) * BK], lane);
    }
  };
  auto stageA = [&](int kc, int buf) {
#pragma unroll
    for (int p2 = 0; p2 < 2; ++p2) {
      int r = rowBase + p2 * 64 + wave * 16 + rsub;
      stage16(Ab + ((size_t)kc * NPAD + r) * 32 + kch,
              &Ash[buf][(p2 * 64 + wave * 16) * BK], lane);
    }
  };
  auto loadA = [&](int kc, float4* f) {
#pragma unroll
    for (int p2 = 0; p2 < 2; ++p2) {
      int r = rowBase + p2 * 64 + wave * 16 + rsub;
      int rs = r < NN ? r : NN - 1;   // clamp: rows >= NN never stored
      const float* xp = Af + (size_t)rs * DIM + kc * 32 + kch;
      f[2 * p2] = *(const float4*)xp;
      f[2 * p2 + 1] = *(const float4*)(xp + 4);
    }
  };
  auto writeA = [&](int buf, const float4* f) {
#pragma unroll
    for (int p2 = 0; p2 < 2; ++p2) {
      float ff[8] = {f[2 * p2].x, f[2 * p2].y, f[2 * p2].z, f[2 * p2].w,
                     f[2 * p2 + 1].x, f[2 * p2 + 1].y, f[2 * p2 + 1].z, f[2 * p2 + 1].w};
      short8 h8, l8;
#pragma unroll
      for (int u = 0; u < 8; ++u) {
        uint16_t hh = f2bf(ff[u]);
        h8[u] = (short)hh;
        l8[u] = (short)f2bf(ff[u] - bf2f(hh));
      }
      *(short8*)&Ash[buf][(p2 * 64 + wave * 16 + rsub) * BK + kch] = h8;
      *(short8*)&Asl[buf][(p2 * 64 + wave * 16 + rsub) * BK + kch] = l8;
    }
  };

  floatx4 acc[4][4];
#pragma unroll
  for (int i = 0; i < 4; ++i)
#pragma unroll
    for (int j = 0; j < 4; ++j) acc[i][j] = (floatx4)(0.0f);

  // prologue: fill buffer 0 with kc=0
  if (SPLIT) {
    float4 f[4];
    loadA(0, f);
    writeA(0, f);
  } else {
    stageA(0, 0);
  }
  stageB(0, 0);
  __syncthreads();

  for (int kc = 0; kc < 8; ++kc) {
    const int cur = kc & 1, nxt = cur ^ 1;
    float4 g4[4];
    if (kc < 7) {                // issue next-tile loads before compute
      if (SPLIT) loadA(kc + 1, g4);
      else stageA(kc + 1, nxt);
      stageB(kc + 1, nxt);
    }

    short8 ah[4], al[4], b[4];
#pragma unroll
    for (int i = 0; i < 4; ++i) {
      int r = wm * 64 + i * 16 + m16;
      ah[i] = *(const short8*)(&Ash[cur][r * BK + q * 8]);
      if (SPLIT) al[i] = *(const short8*)(&Asl[cur][r * BK + q * 8]);
    }
#pragma unroll
    for (int j = 0; j < 4; ++j) {
      int n = wn * 64 + j * 16 + m16;
      b[j] = *(const short8*)(&Bs[cur][n * BK + q * 8]);
    }
#pragma unroll
    for (int i = 0; i < 4; ++i)
#pragma unroll
      for (int j = 0; j < 4; ++j) {
        if (SPLIT)
          acc[i][j] = __builtin_amdgcn_mfma_f32_16x16x32_bf16(al[i], b[j], acc[i][j], 0, 0, 0);
        acc[i][j] = __builtin_amdgcn_mfma_f32_16x16x32_bf16(ah[i], b[j], acc[i][j], 0, 0, 0);
      }

    if (SPLIT && kc < 7) writeA(nxt, g4);  // ds_write next A after MFMA
    __syncthreads();                       // one barrier per K-step
  }

  // epilogue: C/D layout col = lane&15, row = q*4 + reg (verified); chunk-major C
#pragma unroll
  for (int i = 0; i < 4; ++i) {
#pragma unroll
    for (int reg = 0; reg < 4; ++reg) {
      int row = rowBase + wm * 64 + i * 16 + q * 4 + reg;
      if (row < M) {
        float dv = rsqrtf((float)(degp[row] + 1));  // dinv computed inline
#pragma unroll
        for (int j = 0; j < 4; ++j) {
          int col = colBase + wn * 64 + j * 16 + m16;
          C[((size_t)(col >> 5) * NPAD + row) * 32 + (col & 31)] = f2bf(acc[i][j][reg] * dv);
        }
      }
    }
  }
}

// ------ Aggregation: XCD-pinned, degree-sorted, u16 gather list ------
// gb PRE-SCALED (g'[s] = g[s]*dinv[s]), CHUNK-MAJOR [8][NPAD][32]; row ZROW zeroed.
// chunk = blockIdx.x & 7 (round-robin -> each XCD keeps one 3.2 MB chunk L2-resident).
// perm = dests sorted by degree -> the deg>=16 branch is near-wave-uniform.
// gl u16 rows (128 B aligned): dword k holds slots {2k,2k+1}; lane-slot s reads
// dwords {s, s+4, s+8} -> slots 0..23 across the 4 lane-slots. deg<16 skips 2 of
// 6 gathers (46% of dests). Tail (deg>=24, ~3%) loops dwords 12+.
template <int FINAL>
__global__ __launch_bounds__(256) void k_agg(const uint16_t* __restrict__ gb,
                                             const uint16_t* __restrict__ perm,
                                             const uint16_t* __restrict__ gl,
                                             const int* __restrict__ degp,
                                             const float* __restrict__ bias,
                                             const float* __restrict__ x,
                                             uint16_t* __restrict__ outb,
                                             float* __restrict__ outf) {
  const int c = blockIdx.x & 7;            // chunk == XCD slot
  const int dg = blockIdx.x >> 3;          // destination group (16 dests)
  const int wave = threadIdx.x >> 6, lane = threadIdx.x & 63;
  const int dl = lane >> 4;                // dest within wave (0..3)
  const int s = (lane >> 2) & 3;           // lane-slot (0..3)
  const int fl = lane & 3;                 // feat quad: 8 bf16 = 16 B
  const int d = (int)perm[dg * 16 + wave * 4 + dl];
  const int deg = degp[d];
  const uint16_t* gp = gb + (size_t)c * NPAD * 32;
  const uint32_t coff = (uint32_t)fl * 8;  // elem offset within row
  const uint32_t* glr = (const uint32_t*)(gl + (size_t)d * GLC);  // 32 dwords, line-aligned

  uint32_t w0 = glr[s], w1 = glr[s + 4], w2 = glr[s + 8];  // all in line 0 (free-ish)

  auto gat = [&](uint32_t iu) -> uint4v {
    return *(const uint4v*)(gp + iu * 32u + coff);
  };

  float2v acc2[4];
#pragma unroll
  for (int j = 0; j < 4; ++j) acc2[j] = (float2v)(0.0f);

  // slots 0..15 (always)
  uint4v v0 = gat(w0 & 0xffffu), v1 = gat(w0 >> 16);
  uint4v v2 = gat(w1 & 0xffffu), v3 = gat(w1 >> 16);
#pragma unroll
  for (int j = 0; j < 4; ++j) {
    pkacc(acc2[j], v0[j]);
    pkacc(acc2[j], v1[j]);
    pkacc(acc2[j], v2[j]);
    pkacc(acc2[j], v3[j]);
  }
  // slots 16..23 (needed iff deg >= 16; self sits at slot deg)
  if (deg >= 16) {
    uint4v v4 = gat(w2 & 0xffffu), v5 = gat(w2 >> 16);
#pragma unroll
    for (int j = 0; j < 4; ++j) {
      pkacc(acc2[j], v4[j]);
      pkacc(acc2[j], v5[j]);
    }
  }
  // rare tail: slots 24..deg
  if (deg >= 24) {
    for (int k = 12 + s; 2 * k <= deg; k += 4) {
      uint32_t w = glr[k];
      uint4v va = gat(w & 0xffffu), vb = gat(w >> 16);
#pragma unroll
      for (int j = 0; j < 4; ++j) {
        pkacc(acc2[j], va[j]);
        pkacc(acc2[j], vb[j]);
      }
    }
  }

  // reduce across the 4 lane-slots (slot bits are lane bits 2-3)
#pragma unroll
  for (int j = 0; j < 4; ++j) {
    acc2[j][0] += __shfl_xor(acc2[j][0], 4);
    acc2[j][1] += __shfl_xor(acc2[j][1], 4);
    acc2[j][0] += __shfl_xor(acc2[j][0], 8);
    acc2[j][1] += __shfl_xor(acc2[j][1], 8);
  }

  if (s == 0) {
    float dd = rsqrtf((float)(deg + 1));
    int feat = c * 32 + fl * 8;
    float4 b0 = *(const float4*)(bias + feat);
    float4 b1 = *(const float4*)(bias + feat + 4);
    float bb[8] = {b0.x, b0.y, b0.z, b0.w, b1.x, b1.y, b1.z, b1.w};
    float r[8];
#pragma unroll
    for (int j = 0; j < 4; ++j) {
      r[2 * j] = fmaxf(dd * acc2[j][0] + bb[2 * j], 0.f);
      r[2 * j + 1] = fmaxf(dd * acc2[j][1] + bb[2 * j + 1], 0.f);
    }
    if (FINAL) {
      float4 x0 = *(const float4*)(x + (size_t)d * DIM + feat);
      float4 x1 = *(const float4*)(x + (size_t)d * DIM + feat + 4);
      float xx[8] = {x0.x, x0.y, x0.z, x0.w, x1.x, x1.y, x1.z, x1.w};
      float4 o0, o1;
      o0.x = (xx[0] + r[0]) * 0.5f; o0.y = (xx[1] + r[1]) * 0.5f;
      o0.z = (xx[2] + r[2]) * 0.5f; o0.w = (xx[3] + r[3]) * 0.5f;
      o1.x = (xx[4] + r[4]) * 0.5f; o1.y = (xx[5] + r[5]) * 0.5f;
      o1.z = (xx[6] + r[6]) * 0.5f; o1.w = (xx[7] + r[7]) * 0.5f;
      *(float4*)(outf + (size_t)d * DIM + feat) = o0;
      *(float4*)(outf + (size_t)d * DIM + feat + 4) = o1;
    } else {
      ushort8v o;
#pragma unroll
      for (int t = 0; t < 8; ++t) o[t] = f2bf(r[t]);
      *(ushort8v*)(outb + ((size_t)c * NPAD + d) * 32 + fl * 8) = o;
    }
  }
}

// ---------------- launch ----------------
extern "C" void kernel_launch(void* const* d_in, const int* in_sizes, int n_in,
                              void* d_out, int out_size, void* d_ws, size_t ws_size,
                              hipStream_t stream) {
  const float* x  = (const float*)d_in[0];
  const int*   ei = (const int*)d_in[1];   // [2 x NE]: src row, then dst row
  const float* W1 = (const float*)d_in[2];
  const float* b1 = (const float*)d_in[3];
  const float* W2 = (const float*)d_in[4];
  const float* b2 = (const float*)d_in[5];
  float* out = (float*)d_out;

  // workspace layout (16B-aligned); total ~58 MB
  int*      fill   = (int*)d_ws;               // NPAD ints (degree array)
  int*      bins   = fill + NPAD;              // 128 ints (64 bins + 64 cursors)
  uint16_t* perm   = (uint16_t*)(bins + 128);  // NN u16 (100000 B, 16B-aligned)
  uint16_t* gl     = perm + NN;                // NN*GLC u16 = 6.4 MB
  uint16_t* Wt1    = gl + (size_t)NN * GLC;    // 256*256
  uint16_t* Wt2    = Wt1 + 256 * 256;          // 256*256
  uint16_t* g      = Wt2 + 256 * 256;          // [8][NPAD][32] chunk-major
  uint16_t* h1     = g + (size_t)NPAD * DIM;   // [8][NPAD][32]

  const int* esrc = ei;
  const int* edst = ei + NE;

  k_init<<<1691, 256, 0, stream>>>(fill, g, gl, bins, W1, W2, Wt1, Wt2);
  k_fill<<<(NE + 255) / 256, 256, 0, stream>>>(esrc, edst, fill, gl);
  k_degbins<<<196, 256, 0, stream>>>(fill, gl, bins);
  k_scatter<<<196, 256, 0, stream>>>(fill, bins, perm);

  const int aggBlocks = NCHUNK * (NN / 16);  // 8 * 3125 = 25000
  dim3 ggrid(NPAD / BM, 2);                  // (391, 2)
  k_gemm<1><<<ggrid, 256, 0, stream>>>(nullptr, x, Wt1, fill, g, NN);
  k_agg<0><<<aggBlocks, 256, 0, stream>>>(g, perm, gl, fill, b1, nullptr, h1, nullptr);
  k_gemm<0><<<ggrid, 256, 0, stream>>>(h1, nullptr, Wt2, fill, g, NN);
  k_agg<1><<<aggBlocks, 256, 0, stream>>>(g, perm, gl, fill, b2, x, nullptr, out);
}

// Round 10
// 295.846 us; speedup vs baseline: 2.0227x; 2.0227x over previous
//
#include <hip/hip_runtime.h>
#include <stdint.h>

#define NN 50000
#define NPAD 50048   // padded row count; rows NN..NPAD-1 of g are ZEROED (mask rows)
#define NE 800000
#define DIM 256
#define NCHUNK 8     // 8 feature chunks of 32 (64 B bf16) -> one chunk per XCD L2
#define ZROW NN      // zeroed pad row used to mask out-of-degree gathers
#define GLC 64       // u16 slots per dest (128 B row): edges, self at slot deg, rest ZROW

typedef __attribute__((ext_vector_type(8))) short short8;
typedef __attribute__((ext_vector_type(8))) unsigned short ushort8v;
typedef __attribute__((ext_vector_type(4))) float floatx4;
typedef __attribute__((ext_vector_type(2))) float float2v;
typedef __attribute__((ext_vector_type(4))) uint32_t uint4v;
typedef __attribute__((ext_vector_type(4))) int int4v;

__device__ __forceinline__ uint16_t f2bf(float f) {
  union { float f; uint32_t u; } v; v.f = f;
  uint32_t r = v.u + 0x7fffu + ((v.u >> 16) & 1u);
  return (uint16_t)(r >> 16);
}
__device__ __forceinline__ float bf2f(uint16_t h) {
  union { uint32_t u; float f; } v; v.u = ((uint32_t)h) << 16;
  return v.f;
}

// acc pair += (bf16 lo, bf16 hi) of dword u, via packed fp32 add
__device__ __forceinline__ void pkacc(float2v& a, uint32_t u) {
  union { uint32_t u; float f; } lo, hi;
  lo.u = u << 16;
  hi.u = u & 0xffff0000u;
  float2v val;
  val[0] = lo.f;
  val[1] = hi.f;
  asm("v_pk_add_f32 %0, %1, %0" : "+v"(a) : "v"(val));
}

// async global->LDS, 16B per lane; dest = wave-uniform base + lane*16
__device__ __forceinline__ void stage16(const uint16_t* gp, short* lbase, int lane) {
#if __has_builtin(__builtin_amdgcn_global_load_lds)
  __builtin_amdgcn_global_load_lds((__attribute__((address_space(1))) void*)gp,
                                   (__attribute__((address_space(3))) void*)lbase,
                                   16, 0, 0);
#else
  *(ushort8v*)((uint16_t*)lbase + lane * 8) = *(const ushort8v*)gp;
#endif
}

// ---------------- merged init ----------------
// blocks 0..1562: prefill gl(u16) with ZROW (8 u16/thread) + zero fill + zero g pads;
// blocks 1563..1690: transpose W1/W2 -> Wt1/Wt2 (bf16 [n][k]).
__global__ __launch_bounds__(256) void k_init(int* __restrict__ fill, uint16_t* __restrict__ g,
                                              uint16_t* __restrict__ gl,
                                              const float* __restrict__ W1,
                                              const float* __restrict__ W2,
                                              uint16_t* __restrict__ Wt1,
                                              uint16_t* __restrict__ Wt2) {
  __shared__ float t[32][33];
  if (blockIdx.x >= 1563) {  // prep_w part
    int bid = blockIdx.x - 1563;           // 0..127
    const float* W = (bid < 64) ? W1 : W2;
    uint16_t* Wt = (bid < 64) ? Wt1 : Wt2;
    bid &= 63;
    int bx = bid & 7, by = bid >> 3;
    int tx = threadIdx.x & 31, ty = threadIdx.x >> 5;  // 32 x 8
#pragma unroll
    for (int q = 0; q < 4; ++q)
      t[ty + q * 8][tx] = W[(size_t)(by * 32 + ty + q * 8) * 256 + bx * 32 + tx];
    __syncthreads();
#pragma unroll
    for (int q = 0; q < 4; ++q)
      Wt[(size_t)(bx * 32 + ty + q * 8) * 256 + by * 32 + tx] = f2bf(t[tx][ty + q * 8]);
    return;
  }
  int i = blockIdx.x * 256 + threadIdx.x;
  if (i < 400000) {                              // NN*GLC/8 = 400000 ushort8 stores
    ushort8v z8 = {ZROW, ZROW, ZROW, ZROW, ZROW, ZROW, ZROW, ZROW};
    ((ushort8v*)gl)[i] = z8;
  }
  if (i < NPAD / 4) {
    int4v zz = {0, 0, 0, 0};
    ((int4v*)fill)[i] = zz;                      // NPAD/4 = 12512
  }
  if (blockIdx.x < NCHUNK) {
    uint32_t* q = (uint32_t*)(g + ((size_t)blockIdx.x * NPAD + NN) * 32);  // 48*32 u16
    for (int k = threadIdx.x; k < 768; k += 256) q[k] = 0;
  }
}

// fill gather list directly from the edge list; fill[] doubles as degree array
__global__ __launch_bounds__(256) void k_fill(const int* __restrict__ src,
                                              const int* __restrict__ dst,
                                              int* __restrict__ fill,
                                              uint16_t* __restrict__ gl) {
  int e = blockIdx.x * 256 + threadIdx.x;
  if (e < NE) {
    int d = dst[e];
    int old = atomicAdd(&fill[d], 1);
    if (old < GLC - 1) gl[(size_t)d * GLC + old] = (uint16_t)src[e];  // last slot kept for self
  }
}

// ------------- GEMM: BM=128, BN=128, 2-phase double-buffered pipeline -------------
// SPLIT=1: A = x fp32 node-major, hi/lo bf16 split in-register (fused split);
//          also places the self-loop entry gl[d][deg]=d (runs after k_fill, before agg).
// SPLIT=0: A = bf16 chunk-major [8][NPAD][32] via global_load_lds.
// grid (NPAD/128, 2); one barrier per K-step; C chunk-major, pre-scaled by
// dinv(row) = rsqrt(deg+1) computed from fill[] in the epilogue.
#define BM 128
#define BK 32

template <int SPLIT>
__global__ __launch_bounds__(256) void k_gemm(const uint16_t* __restrict__ Ab,
                                              const float* __restrict__ Af,
                                              const uint16_t* __restrict__ Wt,
                                              const int* __restrict__ degp,
                                              uint16_t* __restrict__ gl,
                                              uint16_t* __restrict__ C, int M) {
  __shared__ short Ash[2][BM * BK];   // 16 KB
  __shared__ short Asl[2][BM * BK];   // 16 KB (used only if SPLIT)
  __shared__ short Bs[2][128 * BK];   // 16 KB

  const int tid = threadIdx.x;
  const int wave = tid >> 6, lane = tid & 63;
  const int wm = wave >> 1, wn = wave & 1;
  const int m16 = lane & 15, q = lane >> 4;
  const int rowBase = blockIdx.x * BM;
  const int colBase = blockIdx.y * 128;
  const int rsub = lane >> 2;       // 0..15
  const int kch = (lane & 3) * 8;   // elem offset within 32-chunk

  auto stageB = [&](int kc, int buf) {
#pragma unroll
    for (int p2 = 0; p2 < 2; ++p2) {
      int n = p2 * 64 + wave * 16 + rsub;
      stage16(Wt + (size_t)(colBase + n) * 256 + kc * 32 + kch,
              &Bs[buf][(p2 * 64 + wave * 16) * BK], lane);
    }
  };
  auto stageA = [&](int kc, int buf) {
#pragma unroll
    for (int p2 = 0; p2 < 2; ++p2) {
      int r = rowBase + p2 * 64 + wave * 16 + rsub;
      stage16(Ab + ((size_t)kc * NPAD + r) * 32 + kch,
              &Ash[buf][(p2 * 64 + wave * 16) * BK], lane);
    }
  };
  auto loadA = [&](int kc, float4* f) {
#pragma unroll
    for (int p2 = 0; p2 < 2; ++p2) {
      int r = rowBase + p2 * 64 + wave * 16 + rsub;
      int rs = r < NN ? r : NN - 1;   // clamp: rows >= NN never stored
      const float* xp = Af + (size_t)rs * DIM + kc * 32 + kch;
      f[2 * p2] = *(const float4*)xp;
      f[2 * p2 + 1] = *(const float4*)(xp + 4);
    }
  };
  auto writeA = [&](int buf, const float4* f) {
#pragma unroll
    for (int p2 = 0; p2 < 2; ++p2) {
      float ff[8] = {f[2 * p2].x, f[2 * p2].y, f[2 * p2].z, f[2 * p2].w,
                     f[2 * p2 + 1].x, f[2 * p2 + 1].y, f[2 * p2 + 1].z, f[2 * p2 + 1].w};
      short8 h8, l8;
#pragma unroll
      for (int u = 0; u < 8; ++u) {
        uint16_t hh = f2bf(ff[u]);
        h8[u] = (short)hh;
        l8[u] = (short)f2bf(ff[u] - bf2f(hh));
      }
      *(short8*)&Ash[buf][(p2 * 64 + wave * 16 + rsub) * BK + kch] = h8;
      *(short8*)&Asl[buf][(p2 * 64 + wave * 16 + rsub) * BK + kch] = l8;
    }
  };

  floatx4 acc[4][4];
#pragma unroll
  for (int i = 0; i < 4; ++i)
#pragma unroll
    for (int j = 0; j < 4; ++j) acc[i][j] = (floatx4)(0.0f);

  // SPLIT: place self-loop list entries for this block's rows (was k_deg kernel)
  if (SPLIT && blockIdx.y == 0 && tid < BM) {
    int d = rowBase + tid;
    if (d < NN) {
      int deg = degp[d];
      if (deg < GLC) gl[(size_t)d * GLC + deg] = (uint16_t)d;
    }
  }

  // prologue: fill buffer 0 with kc=0
  if (SPLIT) {
    float4 f[4];
    loadA(0, f);
    writeA(0, f);
  } else {
    stageA(0, 0);
  }
  stageB(0, 0);
  __syncthreads();

  for (int kc = 0; kc < 8; ++kc) {
    const int cur = kc & 1, nxt = cur ^ 1;
    float4 g4[4];
    if (kc < 7) {                // issue next-tile loads before compute
      if (SPLIT) loadA(kc + 1, g4);
      else stageA(kc + 1, nxt);
      stageB(kc + 1, nxt);
    }

    short8 ah[4], al[4], b[4];
#pragma unroll
    for (int i = 0; i < 4; ++i) {
      int r = wm * 64 + i * 16 + m16;
      ah[i] = *(const short8*)(&Ash[cur][r * BK + q * 8]);
      if (SPLIT) al[i] = *(const short8*)(&Asl[cur][r * BK + q * 8]);
    }
#pragma unroll
    for (int j = 0; j < 4; ++j) {
      int n = wn * 64 + j * 16 + m16;
      b[j] = *(const short8*)(&Bs[cur][n * BK + q * 8]);
    }
#pragma unroll
    for (int i = 0; i < 4; ++i)
#pragma unroll
      for (int j = 0; j < 4; ++j) {
        if (SPLIT)
          acc[i][j] = __builtin_amdgcn_mfma_f32_16x16x32_bf16(al[i], b[j], acc[i][j], 0, 0, 0);
        acc[i][j] = __builtin_amdgcn_mfma_f32_16x16x32_bf16(ah[i], b[j], acc[i][j], 0, 0, 0);
      }

    if (SPLIT && kc < 7) writeA(nxt, g4);  // ds_write next A after MFMA
    __syncthreads();                       // one barrier per K-step
  }

  // epilogue: C/D layout col = lane&15, row = q*4 + reg (verified); chunk-major C
#pragma unroll
  for (int i = 0; i < 4; ++i) {
#pragma unroll
    for (int reg = 0; reg < 4; ++reg) {
      int row = rowBase + wm * 64 + i * 16 + q * 4 + reg;
      if (row < M) {
        float dv = rsqrtf((float)(degp[row] + 1));  // dinv computed inline
#pragma unroll
        for (int j = 0; j < 4; ++j) {
          int col = colBase + wn * 64 + j * 16 + m16;
          C[((size_t)(col >> 5) * NPAD + row) * 32 + (col & 31)] = f2bf(acc[i][j][reg] * dv);
        }
      }
    }
  }
}

// ------ Aggregation: XCD-pinned, one-shot over u16 padded gather list ------
// gb PRE-SCALED (g'[s] = g[s]*dinv[s]), CHUNK-MAJOR [8][NPAD][32]; row ZROW zeroed.
// chunk = blockIdx.x & 7 (round-robin -> each XCD keeps one 3.2 MB chunk L2-resident).
// gl u16 rows (128 B aligned): dword k holds slots {2k,2k+1}; lane-slot s reads
// dwords {s, s+4, s+8} -> one-shot covers slots 0..23 (one cache line of indices).
// ZROW pad gathers all hit one L1-resident line (cheap). Tail (deg>=24, ~3%)
// loops dwords 12+. No sort/perm (r9 lesson: hot-address atomics cost >> skip gain).
template <int FINAL>
__global__ __launch_bounds__(256) void k_agg(const uint16_t* __restrict__ gb,
                                             const uint16_t* __restrict__ gl,
                                             const int* __restrict__ degp,
                                             const float* __restrict__ bias,
                                             const float* __restrict__ x,
                                             uint16_t* __restrict__ outb,
                                             float* __restrict__ outf) {
  const int c = blockIdx.x & 7;            // chunk == XCD slot
  const int dg = blockIdx.x >> 3;          // destination group (16 dests)
  const int wave = threadIdx.x >> 6, lane = threadIdx.x & 63;
  const int dl = lane >> 4;                // dest within wave (0..3)
  const int s = (lane >> 2) & 3;           // lane-slot (0..3)
  const int fl = lane & 3;                 // feat quad: 8 bf16 = 16 B
  const int d = dg * 16 + wave * 4 + dl;
  const uint16_t* gp = gb + (size_t)c * NPAD * 32;
  const uint32_t coff = (uint32_t)fl * 8;  // elem offset within row
  const uint32_t* glr = (const uint32_t*)(gl + (size_t)d * GLC);  // 32 dwords, line-aligned

  uint32_t w0 = glr[s], w1 = glr[s + 4], w2 = glr[s + 8];

  auto gat = [&](uint32_t iu) -> uint4v {
    return *(const uint4v*)(gp + iu * 32u + coff);
  };

  // one-shot: slots 0..23 (6 gathers/lane; pads hit the shared ZROW line)
  uint4v v0 = gat(w0 & 0xffffu), v1 = gat(w0 >> 16);
  uint4v v2 = gat(w1 & 0xffffu), v3 = gat(w1 >> 16);
  uint4v v4 = gat(w2 & 0xffffu), v5 = gat(w2 >> 16);

  float2v acc2[4];
#pragma unroll
  for (int j = 0; j < 4; ++j) acc2[j] = (float2v)(0.0f);
#pragma unroll
  for (int j = 0; j < 4; ++j) {
    pkacc(acc2[j], v0[j]);
    pkacc(acc2[j], v1[j]);
    pkacc(acc2[j], v2[j]);
    pkacc(acc2[j], v3[j]);
    pkacc(acc2[j], v4[j]);
    pkacc(acc2[j], v5[j]);
  }

  // rare tail: slots 24..deg (self sits at slot deg)
  int deg = degp[d];
  if (deg >= 24) {
    for (int k = 12 + s; 2 * k <= deg; k += 4) {
      uint32_t w = glr[k];
      uint4v va = gat(w & 0xffffu), vb = gat(w >> 16);
#pragma unroll
      for (int j = 0; j < 4; ++j) {
        pkacc(acc2[j], va[j]);
        pkacc(acc2[j], vb[j]);
      }
    }
  }

  // reduce across the 4 lane-slots (slot bits are lane bits 2-3)
#pragma unroll
  for (int j = 0; j < 4; ++j) {
    acc2[j][0] += __shfl_xor(acc2[j][0], 4);
    acc2[j][1] += __shfl_xor(acc2[j][1], 4);
    acc2[j][0] += __shfl_xor(acc2[j][0], 8);
    acc2[j][1] += __shfl_xor(acc2[j][1], 8);
  }

  if (s == 0) {
    float dd = rsqrtf((float)(deg + 1));
    int feat = c * 32 + fl * 8;
    float4 b0 = *(const float4*)(bias + feat);
    float4 b1 = *(const float4*)(bias + feat + 4);
    float bb[8] = {b0.x, b0.y, b0.z, b0.w, b1.x, b1.y, b1.z, b1.w};
    float r[8];
#pragma unroll
    for (int j = 0; j < 4; ++j) {
      r[2 * j] = fmaxf(dd * acc2[j][0] + bb[2 * j], 0.f);
      r[2 * j + 1] = fmaxf(dd * acc2[j][1] + bb[2 * j + 1], 0.f);
    }
    if (FINAL) {
      float4 x0 = *(const float4*)(x + (size_t)d * DIM + feat);
      float4 x1 = *(const float4*)(x + (size_t)d * DIM + feat + 4);
      float xx[8] = {x0.x, x0.y, x0.z, x0.w, x1.x, x1.y, x1.z, x1.w};
      float4 o0, o1;
      o0.x = (xx[0] + r[0]) * 0.5f; o0.y = (xx[1] + r[1]) * 0.5f;
      o0.z = (xx[2] + r[2]) * 0.5f; o0.w = (xx[3] + r[3]) * 0.5f;
      o1.x = (xx[4] + r[4]) * 0.5f; o1.y = (xx[5] + r[5]) * 0.5f;
      o1.z = (xx[6] + r[6]) * 0.5f; o1.w = (xx[7] + r[7]) * 0.5f;
      *(float4*)(outf + (size_t)d * DIM + feat) = o0;
      *(float4*)(outf + (size_t)d * DIM + feat + 4) = o1;
    } else {
      ushort8v o;
#pragma unroll
      for (int t = 0; t < 8; ++t) o[t] = f2bf(r[t]);
      *(ushort8v*)(outb + ((size_t)c * NPAD + d) * 32 + fl * 8) = o;
    }
  }
}

// ---------------- launch ----------------
extern "C" void kernel_launch(void* const* d_in, const int* in_sizes, int n_in,
                              void* d_out, int out_size, void* d_ws, size_t ws_size,
                              hipStream_t stream) {
  const float* x  = (const float*)d_in[0];
  const int*   ei = (const int*)d_in[1];   // [2 x NE]: src row, then dst row
  const float* W1 = (const float*)d_in[2];
  const float* b1 = (const float*)d_in[3];
  const float* W2 = (const float*)d_in[4];
  const float* b2 = (const float*)d_in[5];
  float* out = (float*)d_out;

  // workspace layout (16B-aligned); total ~58 MB
  int*      fill   = (int*)d_ws;               // NPAD ints (degree array)
  uint16_t* gl     = (uint16_t*)(fill + NPAD); // NN*GLC u16 = 6.4 MB
  uint16_t* Wt1    = gl + (size_t)NN * GLC;    // 256*256
  uint16_t* Wt2    = Wt1 + 256 * 256;          // 256*256
  uint16_t* g      = Wt2 + 256 * 256;          // [8][NPAD][32] chunk-major
  uint16_t* h1     = g + (size_t)NPAD * DIM;   // [8][NPAD][32]

  const int* esrc = ei;
  const int* edst = ei + NE;

  k_init<<<1691, 256, 0, stream>>>(fill, g, gl, W1, W2, Wt1, Wt2);
  k_fill<<<(NE + 255) / 256, 256, 0, stream>>>(esrc, edst, fill, gl);

  const int aggBlocks = NCHUNK * (NN / 16);  // 8 * 3125 = 25000
  dim3 ggrid(NPAD / BM, 2);                  // (391, 2)
  k_gemm<1><<<ggrid, 256, 0, stream>>>(nullptr, x, Wt1, fill, gl, g, NN);
  k_agg<0><<<aggBlocks, 256, 0, stream>>>(g, gl, fill, b1, nullptr, h1, nullptr);
  k_gemm<0><<<ggrid, 256, 0, stream>>>(h1, nullptr, Wt2, fill, nullptr, g, NN);
  k_agg<1><<<aggBlocks, 256, 0, stream>>>(g, gl, fill, b2, x, nullptr, out);
}

// Round 11
// 290.590 us; speedup vs baseline: 2.0593x; 1.0181x over previous
//
#include <hip/hip_runtime.h>
#include <stdint.h>

#define NN 50000
#define NPAD 50048   // padded row count; rows NN..NPAD-1 of g are ZEROED (mask rows)
#define NE 800000
#define DIM 256
#define NCHUNK 8     // 8 feature chunks of 32 (64 B bf16) -> one chunk per XCD L2
#define ZROW NN      // zeroed pad row used to mask out-of-degree gathers
#define GLC 64       // u16 slots per dest (128 B row): edges, self at slot deg, rest ZROW

typedef __attribute__((ext_vector_type(8))) short short8;
typedef __attribute__((ext_vector_type(8))) unsigned short ushort8v;
typedef __attribute__((ext_vector_type(4))) float floatx4;
typedef __attribute__((ext_vector_type(2))) float float2v;
typedef __attribute__((ext_vector_type(4))) uint32_t uint4v;
typedef __attribute__((ext_vector_type(4))) int int4v;

__device__ __forceinline__ uint16_t f2bf(float f) {
  union { float f; uint32_t u; } v; v.f = f;
  uint32_t r = v.u + 0x7fffu + ((v.u >> 16) & 1u);
  return (uint16_t)(r >> 16);
}
__device__ __forceinline__ float bf2f(uint16_t h) {
  union { uint32_t u; float f; } v; v.u = ((uint32_t)h) << 16;
  return v.f;
}

// acc pair += (bf16 lo, bf16 hi) of dword u, via packed fp32 add
__device__ __forceinline__ void pkacc(float2v& a, uint32_t u) {
  union { uint32_t u; float f; } lo, hi;
  lo.u = u << 16;
  hi.u = u & 0xffff0000u;
  float2v val;
  val[0] = lo.f;
  val[1] = hi.f;
  asm("v_pk_add_f32 %0, %1, %0" : "+v"(a) : "v"(val));
}

// async global->LDS, 16B per lane; dest = wave-uniform base + lane*16
__device__ __forceinline__ void stage16(const uint16_t* gp, short* lbase, int lane) {
#if __has_builtin(__builtin_amdgcn_global_load_lds)
  __builtin_amdgcn_global_load_lds((__attribute__((address_space(1))) void*)gp,
                                   (__attribute__((address_space(3))) void*)lbase,
                                   16, 0, 0);
#else
  *(ushort8v*)((uint16_t*)lbase + lane * 8) = *(const ushort8v*)gp;
#endif
}

// ---------------- merged init ----------------
// blocks 0..1562: prefill gl(u16) with ZROW (8 u16/thread) + zero fill + zero g pads;
// blocks 1563..1690: transpose W1/W2 -> Wt1/Wt2 (bf16 [n][k]).
__global__ __launch_bounds__(256) void k_init(int* __restrict__ fill, uint16_t* __restrict__ g,
                                              uint16_t* __restrict__ gl,
                                              const float* __restrict__ W1,
                                              const float* __restrict__ W2,
                                              uint16_t* __restrict__ Wt1,
                                              uint16_t* __restrict__ Wt2) {
  __shared__ float t[32][33];
  if (blockIdx.x >= 1563) {  // prep_w part
    int bid = blockIdx.x - 1563;           // 0..127
    const float* W = (bid < 64) ? W1 : W2;
    uint16_t* Wt = (bid < 64) ? Wt1 : Wt2;
    bid &= 63;
    int bx = bid & 7, by = bid >> 3;
    int tx = threadIdx.x & 31, ty = threadIdx.x >> 5;  // 32 x 8
#pragma unroll
    for (int q = 0; q < 4; ++q)
      t[ty + q * 8][tx] = W[(size_t)(by * 32 + ty + q * 8) * 256 + bx * 32 + tx];
    __syncthreads();
#pragma unroll
    for (int q = 0; q < 4; ++q)
      Wt[(size_t)(bx * 32 + ty + q * 8) * 256 + by * 32 + tx] = f2bf(t[tx][ty + q * 8]);
    return;
  }
  int i = blockIdx.x * 256 + threadIdx.x;
  if (i < 400000) {                              // NN*GLC/8 = 400000 ushort8 stores
    ushort8v z8 = {ZROW, ZROW, ZROW, ZROW, ZROW, ZROW, ZROW, ZROW};
    ((ushort8v*)gl)[i] = z8;
  }
  if (i < NPAD / 4) {
    int4v zz = {0, 0, 0, 0};
    ((int4v*)fill)[i] = zz;                      // NPAD/4 = 12512
  }
  if (blockIdx.x < NCHUNK) {
    uint32_t* q = (uint32_t*)(g + ((size_t)blockIdx.x * NPAD + NN) * 32);  // 48*32 u16
    for (int k = threadIdx.x; k < 768; k += 256) q[k] = 0;
  }
}

// fill gather list directly from the edge list; fill[] doubles as degree array
__global__ __launch_bounds__(256) void k_fill(const int* __restrict__ src,
                                              const int* __restrict__ dst,
                                              int* __restrict__ fill,
                                              uint16_t* __restrict__ gl) {
  int e = blockIdx.x * 256 + threadIdx.x;
  if (e < NE) {
    int d = dst[e];
    int old = atomicAdd(&fill[d], 1);
    if (old < GLC - 1) gl[(size_t)d * GLC + old] = (uint16_t)src[e];  // last slot kept for self
  }
}

// ------------- GEMM: BM=64, BN=256 (full width, A read ONCE), dbuf pipeline -------------
// SPLIT=1: A = x fp32 node-major, hi/lo bf16 split in-register (fused split);
//          also places the self-loop entry gl[d][deg]=d (runs after k_fill, before agg).
// SPLIT=0: A = bf16 chunk-major [8][NPAD][32] via global_load_lds.
// B (0.13 MB) is L2-resident; re-staging it per block is cheap. A is the big stream:
// full-width BN=256 reads x / h1 exactly once (r7's 128x128 read A twice -- reverted).
// One barrier per K-step; C chunk-major, pre-scaled by dinv(row)=rsqrt(deg+1).
#define BM 64
#define BK 32

template <int SPLIT>
__global__ __launch_bounds__(256) void k_gemm(const uint16_t* __restrict__ Ab,
                                              const float* __restrict__ Af,
                                              const uint16_t* __restrict__ Wt,
                                              const int* __restrict__ degp,
                                              uint16_t* __restrict__ gl,
                                              uint16_t* __restrict__ C, int M) {
  __shared__ short Ash[2][BM * BK];   // 8 KB
  __shared__ short Asl[2][BM * BK];   // 8 KB (used only if SPLIT)
  __shared__ short Bs[2][256 * BK];   // 32 KB

  const int tid = threadIdx.x;
  const int wave = tid >> 6, lane = tid & 63;
  const int m16 = lane & 15, q = lane >> 4;
  const int rowBase = blockIdx.x * BM;
  const int rsub = lane >> 2;       // 0..15
  const int kch = (lane & 3) * 8;   // elem offset within 32-chunk

  auto stageB = [&](int kc, int buf) {
#pragma unroll
    for (int p2 = 0; p2 < 4; ++p2) {
      int n = p2 * 64 + wave * 16 + rsub;
      stage16(Wt + (size_t)n * 256 + kc * 32 + kch, &Bs[buf][(p2 * 64 + wave * 16) * BK], lane);
    }
  };
  auto stageA = [&](int kc, int buf) {
    int r = rowBase + wave * 16 + rsub;
    stage16(Ab + ((size_t)kc * NPAD + r) * 32 + kch, &Ash[buf][(wave * 16) * BK], lane);
  };
  auto loadA = [&](int kc, float4& f0, float4& f1) {
    int r = rowBase + wave * 16 + rsub;
    int rs = r < NN ? r : NN - 1;   // clamp: rows >= NN never stored
    const float* xp = Af + (size_t)rs * DIM + kc * 32 + kch;
    f0 = *(const float4*)xp;
    f1 = *(const float4*)(xp + 4);
  };
  auto writeA = [&](int buf, const float4& f0, const float4& f1) {
    float ff[8] = {f0.x, f0.y, f0.z, f0.w, f1.x, f1.y, f1.z, f1.w};
    short8 h8, l8;
#pragma unroll
    for (int u = 0; u < 8; ++u) {
      uint16_t hh = f2bf(ff[u]);
      h8[u] = (short)hh;
      l8[u] = (short)f2bf(ff[u] - bf2f(hh));
    }
    *(short8*)&Ash[buf][(wave * 16 + rsub) * BK + kch] = h8;
    *(short8*)&Asl[buf][(wave * 16 + rsub) * BK + kch] = l8;
  };

  floatx4 acc[4][4];
#pragma unroll
  for (int i = 0; i < 4; ++i)
#pragma unroll
    for (int j = 0; j < 4; ++j) acc[i][j] = (floatx4)(0.0f);

  // SPLIT: place self-loop list entries for this block's rows (replaces k_deg kernel)
  if (SPLIT && tid < BM) {
    int d = rowBase + tid;
    if (d < NN) {
      int deg = degp[d];
      if (deg < GLC) gl[(size_t)d * GLC + deg] = (uint16_t)d;
    }
  }

  // prologue: fill buffer 0 with kc=0
  if (SPLIT) {
    float4 f0, f1;
    loadA(0, f0, f1);
    writeA(0, f0, f1);
  } else {
    stageA(0, 0);
  }
  stageB(0, 0);
  __syncthreads();

  for (int kc = 0; kc < 8; ++kc) {
    const int cur = kc & 1, nxt = cur ^ 1;
    float4 g0, g1;
    if (kc < 7) {                // issue next-tile loads before compute
      if (SPLIT) loadA(kc + 1, g0, g1);
      else stageA(kc + 1, nxt);
      stageB(kc + 1, nxt);
    }

    short8 ah[4], al[4], b[4];
#pragma unroll
    for (int i = 0; i < 4; ++i) {
      int r = i * 16 + m16;
      ah[i] = *(const short8*)(&Ash[cur][r * BK + q * 8]);
      if (SPLIT) al[i] = *(const short8*)(&Asl[cur][r * BK + q * 8]);
    }
#pragma unroll
    for (int j = 0; j < 4; ++j) {
      int n = wave * 64 + j * 16 + m16;
      b[j] = *(const short8*)(&Bs[cur][n * BK + q * 8]);
    }
#pragma unroll
    for (int i = 0; i < 4; ++i)
#pragma unroll
      for (int j = 0; j < 4; ++j) {
        if (SPLIT)
          acc[i][j] = __builtin_amdgcn_mfma_f32_16x16x32_bf16(al[i], b[j], acc[i][j], 0, 0, 0);
        acc[i][j] = __builtin_amdgcn_mfma_f32_16x16x32_bf16(ah[i], b[j], acc[i][j], 0, 0, 0);
      }

    if (SPLIT && kc < 7) writeA(nxt, g0, g1);  // ds_write next A after MFMA
    __syncthreads();                           // one barrier per K-step
  }

  // epilogue: C/D layout col = lane&15, row = q*4 + reg (verified); chunk-major C
#pragma unroll
  for (int i = 0; i < 4; ++i) {
#pragma unroll
    for (int reg = 0; reg < 4; ++reg) {
      int row = rowBase + i * 16 + q * 4 + reg;
      if (row < M) {
        float dv = rsqrtf((float)(degp[row] + 1));  // dinv computed inline
#pragma unroll
        for (int j = 0; j < 4; ++j) {
          int col = wave * 64 + j * 16 + m16;
          C[((size_t)(col >> 5) * NPAD + row) * 32 + (col & 31)] = f2bf(acc[i][j][reg] * dv);
        }
      }
    }
  }
}

// ------ Aggregation: XCD-pinned, one-shot over u16 padded gather list ------
// gb PRE-SCALED (g'[s] = g[s]*dinv[s]), CHUNK-MAJOR [8][NPAD][32]; row ZROW zeroed.
// chunk = blockIdx.x & 7 (round-robin -> each XCD keeps one 3.2 MB chunk L2-resident).
// gl u16 rows (128 B aligned): dword k holds slots {2k,2k+1}; lane-slot s reads
// dwords {s, s+4, s+8} -> one-shot covers slots 0..23 (one cache line of indices).
// ZROW pad gathers all hit one L1-resident line (cheap). Tail (deg>=24, ~3%)
// loops dwords 12+. NOTE: invariant 56.6 us across u32/u16 lists and 59-65%
// occupancy -> limited by per-CU scattered-address rate (bytes & addresses are
// algorithmically fixed). Do not expect schedule tweaks to move it.
template <int FINAL>
__global__ __launch_bounds__(256) void k_agg(const uint16_t* __restrict__ gb,
                                             const uint16_t* __restrict__ gl,
                                             const int* __restrict__ degp,
                                             const float* __restrict__ bias,
                                             const float* __restrict__ x,
                                             uint16_t* __restrict__ outb,
                                             float* __restrict__ outf) {
  const int c = blockIdx.x & 7;            // chunk == XCD slot
  const int dg = blockIdx.x >> 3;          // destination group (16 dests)
  const int wave = threadIdx.x >> 6, lane = threadIdx.x & 63;
  const int dl = lane >> 4;                // dest within wave (0..3)
  const int s = (lane >> 2) & 3;           // lane-slot (0..3)
  const int fl = lane & 3;                 // feat quad: 8 bf16 = 16 B
  const int d = dg * 16 + wave * 4 + dl;
  const uint16_t* gp = gb + (size_t)c * NPAD * 32;
  const uint32_t coff = (uint32_t)fl * 8;  // elem offset within row
  const uint32_t* glr = (const uint32_t*)(gl + (size_t)d * GLC);  // 32 dwords, line-aligned

  uint32_t w0 = glr[s], w1 = glr[s + 4], w2 = glr[s + 8];

  auto gat = [&](uint32_t iu) -> uint4v {
    return *(const uint4v*)(gp + iu * 32u + coff);
  };

  // one-shot: slots 0..23 (6 gathers/lane; pads hit the shared ZROW line)
  uint4v v0 = gat(w0 & 0xffffu), v1 = gat(w0 >> 16);
  uint4v v2 = gat(w1 & 0xffffu), v3 = gat(w1 >> 16);
  uint4v v4 = gat(w2 & 0xffffu), v5 = gat(w2 >> 16);

  float2v acc2[4];
#pragma unroll
  for (int j = 0; j < 4; ++j) acc2[j] = (float2v)(0.0f);
#pragma unroll
  for (int j = 0; j < 4; ++j) {
    pkacc(acc2[j], v0[j]);
    pkacc(acc2[j], v1[j]);
    pkacc(acc2[j], v2[j]);
    pkacc(acc2[j], v3[j]);
    pkacc(acc2[j], v4[j]);
    pkacc(acc2[j], v5[j]);
  }

  // rare tail: slots 24..deg (self sits at slot deg)
  int deg = degp[d];
  if (deg >= 24) {
    for (int k = 12 + s; 2 * k <= deg; k += 4) {
      uint32_t w = glr[k];
      uint4v va = gat(w & 0xffffu), vb = gat(w >> 16);
#pragma unroll
      for (int j = 0; j < 4; ++j) {
        pkacc(acc2[j], va[j]);
        pkacc(acc2[j], vb[j]);
      }
    }
  }

  // reduce across the 4 lane-slots (slot bits are lane bits 2-3)
#pragma unroll
  for (int j = 0; j < 4; ++j) {
    acc2[j][0] += __shfl_xor(acc2[j][0], 4);
    acc2[j][1] += __shfl_xor(acc2[j][1], 4);
    acc2[j][0] += __shfl_xor(acc2[j][0], 8);
    acc2[j][1] += __shfl_xor(acc2[j][1], 8);
  }

  if (s == 0) {
    float dd = rsqrtf((float)(deg + 1));
    int feat = c * 32 + fl * 8;
    float4 b0 = *(const float4*)(bias + feat);
    float4 b1 = *(const float4*)(bias + feat + 4);
    float bb[8] = {b0.x, b0.y, b0.z, b0.w, b1.x, b1.y, b1.z, b1.w};
    float r[8];
#pragma unroll
    for (int j = 0; j < 4; ++j) {
      r[2 * j] = fmaxf(dd * acc2[j][0] + bb[2 * j], 0.f);
      r[2 * j + 1] = fmaxf(dd * acc2[j][1] + bb[2 * j + 1], 0.f);
    }
    if (FINAL) {
      float4 x0 = *(const float4*)(x + (size_t)d * DIM + feat);
      float4 x1 = *(const float4*)(x + (size_t)d * DIM + feat + 4);
      float xx[8] = {x0.x, x0.y, x0.z, x0.w, x1.x, x1.y, x1.z, x1.w};
      float4 o0, o1;
      o0.x = (xx[0] + r[0]) * 0.5f; o0.y = (xx[1] + r[1]) * 0.5f;
      o0.z = (xx[2] + r[2]) * 0.5f; o0.w = (xx[3] + r[3]) * 0.5f;
      o1.x = (xx[4] + r[4]) * 0.5f; o1.y = (xx[5] + r[5]) * 0.5f;
      o1.z = (xx[6] + r[6]) * 0.5f; o1.w = (xx[7] + r[7]) * 0.5f;
      *(float4*)(outf + (size_t)d * DIM + feat) = o0;
      *(float4*)(outf + (size_t)d * DIM + feat + 4) = o1;
    } else {
      ushort8v o;
#pragma unroll
      for (int t = 0; t < 8; ++t) o[t] = f2bf(r[t]);
      *(ushort8v*)(outb + ((size_t)c * NPAD + d) * 32 + fl * 8) = o;
    }
  }
}

// ---------------- launch ----------------
extern "C" void kernel_launch(void* const* d_in, const int* in_sizes, int n_in,
                              void* d_out, int out_size, void* d_ws, size_t ws_size,
                              hipStream_t stream) {
  const float* x  = (const float*)d_in[0];
  const int*   ei = (const int*)d_in[1];   // [2 x NE]: src row, then dst row
  const float* W1 = (const float*)d_in[2];
  const float* b1 = (const float*)d_in[3];
  const float* W2 = (const float*)d_in[4];
  const float* b2 = (const float*)d_in[5];
  float* out = (float*)d_out;

  // workspace layout (16B-aligned); total ~58 MB
  int*      fill   = (int*)d_ws;               // NPAD ints (degree array)
  uint16_t* gl     = (uint16_t*)(fill + NPAD); // NN*GLC u16 = 6.4 MB
  uint16_t* Wt1    = gl + (size_t)NN * GLC;    // 256*256
  uint16_t* Wt2    = Wt1 + 256 * 256;          // 256*256
  uint16_t* g      = Wt2 + 256 * 256;          // [8][NPAD][32] chunk-major
  uint16_t* h1     = g + (size_t)NPAD * DIM;   // [8][NPAD][32]

  const int* esrc = ei;
  const int* edst = ei + NE;

  k_init<<<1691, 256, 0, stream>>>(fill, g, gl, W1, W2, Wt1, Wt2);
  k_fill<<<(NE + 255) / 256, 256, 0, stream>>>(esrc, edst, fill, gl);

  const int aggBlocks = NCHUNK * (NN / 16);  // 8 * 3125 = 25000
  const int gemmBlocks = NPAD / BM;          // 782
  k_gemm<1><<<gemmBlocks, 256, 0, stream>>>(nullptr, x, Wt1, fill, gl, g, NN);
  k_agg<0><<<aggBlocks, 256, 0, stream>>>(g, gl, fill, b1, nullptr, h1, nullptr);
  k_gemm<0><<<gemmBlocks, 256, 0, stream>>>(h1, nullptr, Wt2, fill, nullptr, g, NN);
  k_agg<1><<<aggBlocks, 256, 0, stream>>>(g, gl, fill, b2, x, nullptr, out);
}